// Round 5
// baseline (866.684 us; speedup 1.0000x reference)
//
#include <hip/hip_runtime.h>

typedef _Float16 half8 __attribute__((ext_vector_type(8)));
typedef float floatx4 __attribute__((ext_vector_type(4)));

#define BATCH 131072
#define S_DIM 376
#define NACT 17

// padded weight plane geometry (transposed [n][k], zero-padded)
#define W1N 448
#define W1K 384
#define W2N 320
#define W2K 416
#define W3N 256
#define W3K 320

// ws offsets in halfs
#define W1HI 0
#define W1LO (W1N * W1K)
#define W2HI (2 * W1N * W1K)
#define W2LO (W2HI + W2N * W2K)
#define W3HI (W2HI + 2 * W2N * W2K)
#define W3LO (W3HI + W3N * W3K)

// padded LDS strides (halfs / floats) chosen so row-stride mod 32 banks != 0/16:
// 424 halfs = 848 B -> 212 words, mod 32 = 20 (2-way max, free)
// 328 halfs = 656 B -> 164 words, mod 32 = 4
// 260 floats = 1040 B -> 260 words, mod 32 = 4
#define AW1 424
#define AW2 328
#define OW3 260

#define MFMA16(a, b, c) __builtin_amdgcn_mfma_f32_16x16x32_f16(a, b, c, 0, 0, 0)

// ---------------- prep: split fp32 weights into (hi,lo) fp16 planes, transposed, padded ----------------
// k-major thread index -> coalesced global reads (consecutive lanes read consecutive n).
__global__ __launch_bounds__(256) void prep_kernel(const float* __restrict__ W1,
                                                   const float* __restrict__ W2,
                                                   const float* __restrict__ W3,
                                                   _Float16* __restrict__ ws) {
  const int idx = blockIdx.x * 256 + threadIdx.x;
  float v;
  int hioff, looff;
  if (idx < W1K * W1N) {                       // idx = k*448 + n
    int k = idx / W1N, n = idx - k * W1N;
    v = (n < 400 && k < 376) ? W1[k * 400 + n] : 0.f;
    hioff = W1HI + n * W1K + k; looff = W1LO + n * W1K + k;
  } else if (idx < W1K * W1N + W2K * W2N) {    // idx2 = k*320 + n
    int e = idx - W1K * W1N;
    int k = e / W2N, n = e - k * W2N;
    v = (n < 300 && k < 400) ? W2[k * 300 + n] : 0.f;
    hioff = W2HI + n * W2K + k; looff = W2LO + n * W2K + k;
  } else if (idx < W1K * W1N + W2K * W2N + W3K * W3N) {  // idx3 = k*256 + n
    int e = idx - W1K * W1N - W2K * W2N;
    int k = e >> 8, n = e & 255;
    v = (n < 255 && k < 300) ? W3[k * 255 + n] : 0.f;
    hioff = W3HI + n * W3K + k; looff = W3LO + n * W3K + k;
  } else {
    return;
  }
  _Float16 hi = (_Float16)v;
  ws[hioff] = hi;
  ws[looff] = (_Float16)(v - (float)hi);
}

// ---------------- barrier-free, chunk-double-buffered GEMM body ----------------
// A (hi/lo fp16 planes) from LDS (stride AW halfs); B (hi/lo planes) direct from
// global ws (stride KP halfs). Wave owns NT column tiles x 4 row tiles (64 rows).
// Full-chunk register double-buffer: all of chunk kc+1's loads (2*NT global b128 +
// 8 ds_read_b128) issue before chunk kc's 12*NT MFMAs -> ~400 cyc of compute covers
// ~200 cyc L2 / ~120 cyc LDS latency with 1 wave/SIMD. No __syncthreads inside.
template <int NT, int CHUNKS, int AW, int KP>
__device__ __forceinline__ void gemm_layer(const _Float16* __restrict__ Ahi,
                                           const _Float16* __restrict__ Alo,
                                           const _Float16* __restrict__ Bhi,
                                           const _Float16* __restrict__ Blo,
                                           int ntm,  // ntBase*16 + m
                                           int q, int m, floatx4 (&acc)[4][NT]) {
  const int kq = q * 8;
  const _Float16* bhp = Bhi + ntm * KP + kq;
  const _Float16* blp = Blo + ntm * KP + kq;
  const _Float16* ahp = Ahi + m * AW + kq;
  const _Float16* alp = Alo + m * AW + kq;

  half8 b0h[NT], b0l[NT], b1h[NT], b1l[NT];
  half8 a0h[4], a0l[4], a1h[4], a1l[4];

  auto loadB = [&](half8 (&dh)[NT], half8 (&dl)[NT], int kc) {
    const int ko = kc * 32;
#pragma unroll
    for (int nt = 0; nt < NT; ++nt) {
      dh[nt] = *(const half8*)(bhp + nt * 16 * KP + ko);
      dl[nt] = *(const half8*)(blp + nt * 16 * KP + ko);
    }
  };
  auto loadA = [&](half8 (&dh)[4], half8 (&dl)[4], int kc) {
    const int ko = kc * 32;
#pragma unroll
    for (int mt = 0; mt < 4; ++mt) {
      dh[mt] = *(const half8*)(ahp + mt * 16 * AW + ko);
      dl[mt] = *(const half8*)(alp + mt * 16 * AW + ko);
    }
  };
  auto comp = [&](half8 (&xh)[4], half8 (&xl)[4], half8 (&yh)[NT], half8 (&yl)[NT]) {
#pragma unroll
    for (int nt = 0; nt < NT; ++nt) {
#pragma unroll
      for (int mt = 0; mt < 4; ++mt) acc[mt][nt] = MFMA16(xh[mt], yh[nt], acc[mt][nt]);
#pragma unroll
      for (int mt = 0; mt < 4; ++mt) acc[mt][nt] = MFMA16(xh[mt], yl[nt], acc[mt][nt]);
#pragma unroll
      for (int mt = 0; mt < 4; ++mt) acc[mt][nt] = MFMA16(xl[mt], yh[nt], acc[mt][nt]);
    }
  };

  loadB(b0h, b0l, 0);
  loadA(a0h, a0l, 0);
  constexpr int PAIRS = CHUNKS / 2;
  for (int p = 0; p < PAIRS; ++p) {
    const int k1 = 2 * p + 1, k2 = 2 * p + 2;
    loadB(b1h, b1l, k1);
    loadA(a1h, a1l, k1);
    comp(a0h, a0l, b0h, b0l);
    if (k2 < CHUNKS) {
      loadB(b0h, b0l, k2);
      loadA(a0h, a0l, k2);
    }
    comp(a1h, a1l, b1h, b1l);
  }
  if (CHUNKS & 1) comp(a0h, a0l, b0h, b0l);  // last chunk already resident in buf0
}

// ---------------- fused actor kernel ----------------
// Block: 256 thr / 4 waves / 64 batch rows. Waves split N (n_s=4): each B fragment
// is read by exactly one wave -> B streams from global (L2-resident weights); LDS
// holds only A/h planes. Overlay: Astage[64][424]pair -> H1 -> H2[64][328]pair -> O3[64][260]f32.
__global__ __launch_bounds__(256, 1) void actor_kernel(const float* __restrict__ state,
                                                       const float* __restrict__ eps,
                                                       const float* __restrict__ b1,
                                                       const float* __restrict__ b2,
                                                       const float* __restrict__ b3,
                                                       const _Float16* __restrict__ wsp,
                                                       float* __restrict__ out) {
  extern __shared__ char smem[];
  _Float16* Ahi = (_Float16*)smem;               // [64][424]
  _Float16* Alo = Ahi + 64 * AW1;

  const int t = threadIdx.x;
  const int wave = t >> 6;
  const int lane = t & 63;
  const int q = lane >> 4;
  const int m = lane & 15;
  const long rowbase = (long)blockIdx.x * 64;

  // ---- stage state into LDS as split-fp16 pair (once per block) ----
  {
    const int row = t >> 2, p = t & 3;
    const long gbase = (rowbase + row) * S_DIM;
    for (int c0 = 0; c0 < 12; ++c0) {
      const int col = c0 * 32 + p * 8;
      float v[8];
      if (col + 8 <= S_DIM) {
        const float4* sp = (const float4*)(state + gbase + col);
        float4 x0 = sp[0], x1 = sp[1];
        v[0] = x0.x; v[1] = x0.y; v[2] = x0.z; v[3] = x0.w;
        v[4] = x1.x; v[5] = x1.y; v[6] = x1.z; v[7] = x1.w;
      } else {
#pragma unroll
        for (int j = 0; j < 8; ++j) v[j] = 0.f;
      }
      half8 h, l;
#pragma unroll
      for (int j = 0; j < 8; ++j) {
        _Float16 hi = (_Float16)v[j];
        h[j] = hi;
        l[j] = (_Float16)(v[j] - (float)hi);
      }
      *(half8*)(Ahi + row * AW1 + col) = h;
      *(half8*)(Alo + row * AW1 + col) = l;
    }
  }
  __syncthreads();

  // ================= Layer 1 =================
  floatx4 acc1[4][7];
#pragma unroll
  for (int a = 0; a < 4; ++a)
#pragma unroll
    for (int b = 0; b < 7; ++b) { acc1[a][b][0] = 0.f; acc1[a][b][1] = 0.f; acc1[a][b][2] = 0.f; acc1[a][b][3] = 0.f; }
  gemm_layer<7, 12, AW1, W1K>(Ahi, Alo, wsp + W1HI, wsp + W1LO, wave * 112 + m, q, m, acc1);

  __syncthreads();  // all A reads done -> overlay h1 into same region
  _Float16* H1hi = Ahi;   // [64][424], cols 0..415 valid
  _Float16* H1lo = Alo;
#pragma unroll
  for (int nt = 0; nt < 7; ++nt) {
    const int tile = wave * 7 + nt;
    if (tile < 26) {                 // tile 25 writes the zero pad cols 400..415
      const int col = tile * 16 + m;
      const float bias = (col < 400) ? b1[col] : 0.f;
#pragma unroll
      for (int mt = 0; mt < 4; ++mt)
#pragma unroll
        for (int r = 0; r < 4; ++r) {
          const int row = mt * 16 + q * 4 + r;
          float v = fmaxf(acc1[mt][nt][r] + bias, 0.f);
          _Float16 hi = (_Float16)v;
          H1hi[row * AW1 + col] = hi;
          H1lo[row * AW1 + col] = (_Float16)(v - (float)hi);
        }
    }
  }
  __syncthreads();

  // ================= Layer 2 =================
  floatx4 acc2[4][5];
#pragma unroll
  for (int a = 0; a < 4; ++a)
#pragma unroll
    for (int b = 0; b < 5; ++b) { acc2[a][b][0] = 0.f; acc2[a][b][1] = 0.f; acc2[a][b][2] = 0.f; acc2[a][b][3] = 0.f; }
  gemm_layer<5, 13, AW1, W2K>(H1hi, H1lo, wsp + W2HI, wsp + W2LO, wave * 80 + m, q, m, acc2);

  __syncthreads();  // all h1 reads done -> overlay h2
  _Float16* H2hi = (_Float16*)smem;  // [64][328], cols 0..319 valid
  _Float16* H2lo = H2hi + 64 * AW2;
#pragma unroll
  for (int nt = 0; nt < 5; ++nt) {
    const int col = (wave * 5 + nt) * 16 + m;   // < 320; cols >=300 get zeros (padded W2/b2)
    const float bias = (col < 300) ? b2[col] : 0.f;
#pragma unroll
    for (int mt = 0; mt < 4; ++mt)
#pragma unroll
      for (int r = 0; r < 4; ++r) {
        const int row = mt * 16 + q * 4 + r;
        float v = fmaxf(acc2[mt][nt][r] + bias, 0.f);
        _Float16 hi = (_Float16)v;
        H2hi[row * AW2 + col] = hi;
        H2lo[row * AW2 + col] = (_Float16)(v - (float)hi);
      }
  }
  __syncthreads();

  // ================= Layer 3 =================
  floatx4 acc3[4][4];
#pragma unroll
  for (int a = 0; a < 4; ++a)
#pragma unroll
    for (int b = 0; b < 4; ++b) { acc3[a][b][0] = 0.f; acc3[a][b][1] = 0.f; acc3[a][b][2] = 0.f; acc3[a][b][3] = 0.f; }
  gemm_layer<4, 10, AW2, W3K>(H2hi, H2lo, wsp + W3HI, wsp + W3LO, wave * 64 + m, q, m, acc3);

  __syncthreads();  // all h2 reads done -> overlay O3
  float* O3 = (float*)smem;  // [64][260] fp32
#pragma unroll
  for (int nt = 0; nt < 4; ++nt) {
    const int col = (wave * 4 + nt) * 16 + m;
    const float bias = (col < 255) ? b3[col] : 0.f;
#pragma unroll
    for (int mt = 0; mt < 4; ++mt)
#pragma unroll
      for (int r = 0; r < 4; ++r) {
        const int row = mt * 16 + q * 4 + r;
        O3[row * OW3 + col] = tanhf(acc3[mt][nt][r] + bias);
      }
  }
  __syncthreads();

  // ================= Epilogue: mixture stats, sample, logprobs =================
  {
    const int row = t >> 2, p = t & 3;   // 4 threads per batch row
    const long gr = rowbase + row;
    const float* Or = O3 + row * OW3;
    float pc = 0.f, pt = 0.f, pe = 0.f;
    const int nact = (p == 0) ? 5 : 4;
    for (int ia = 0; ia < nact; ++ia) {
      const int a = p + ia * 4;          // p==0 also covers a=16
      float mw[5], mmv[5], lms[5];
#pragma unroll
      for (int j = 0; j < 5; ++j) {
        mw[j]  = Or[a * 5 + j];
        mmv[j] = Or[85 + a * 5 + j];
        lms[j] = Or[170 + a * 5 + j];
      }
      float w[5], es = 0.f;
#pragma unroll
      for (int j = 0; j < 5; ++j) { w[j] = expf(mw[j]); es += w[j]; }
      const float inv = 1.f / es;
      float mean = 0.f;
#pragma unroll
      for (int j = 0; j < 5; ++j) { w[j] *= inv; mean += w[j] * mmv[j]; }
      float alea = 0.f, epis = 0.f;
#pragma unroll
      for (int j = 0; j < 5; ++j) {
        float sd = expf(fminf(fmaxf(lms[j], -10.f), 2.f));
        alea += w[j] * sd;
        float d = mmv[j] - mean;
        epis += w[j] * d * d;
      }
      epis = fminf(fmaxf(epis, 4.53999297624848e-05f), 7.38905609893065f);
      const float total = alea + epis;
      const float ea = eps[gr * NACT + a];
      const float sample = mean + total * ea;
      const float ts = tanhf(sample);
      out[gr * NACT + a] = ts;
      pc += logf(1.f - ts * ts + 1e-6f);
      const float dz = sample - mean;
      const float zt = dz / total;
      const float ze = dz / epis;
      pt += zt * zt + 2.f * logf(total);
      pe += ze * ze + 2.f * logf(epis);
    }
    pc += __shfl_xor(pc, 1); pc += __shfl_xor(pc, 2);
    pt += __shfl_xor(pt, 1); pt += __shfl_xor(pt, 2);
    pe += __shfl_xor(pe, 1); pe += __shfl_xor(pe, 2);
    if (p == 0) {
      const float hdl2pi = 15.62195506447944f;  // 0.5*17*ln(2*pi)
      out[(long)NACT * BATCH + gr] = (-0.5f * pt - hdl2pi) - pc;
      out[(long)(NACT + 1) * BATCH + gr] = (-0.5f * pe - hdl2pi) - pc;
    }
  }
}

extern "C" void kernel_launch(void* const* d_in, const int* in_sizes, int n_in,
                              void* d_out, int out_size, void* d_ws, size_t ws_size,
                              hipStream_t stream) {
  const float* state = (const float*)d_in[0];
  const float* eps   = (const float*)d_in[1];
  const float* W1    = (const float*)d_in[2];
  const float* b1    = (const float*)d_in[3];
  const float* W2    = (const float*)d_in[4];
  const float* b2    = (const float*)d_in[5];
  const float* W3    = (const float*)d_in[6];
  const float* b3    = (const float*)d_in[7];
  float* out = (float*)d_out;
  _Float16* ws = (_Float16*)d_ws;

  (void)in_sizes; (void)n_in; (void)out_size; (void)ws_size;

  // LDS: 64*424*2 planes*2B = 108,544 B (A/H1 region is the max overlay)
  hipFuncSetAttribute(reinterpret_cast<const void*>(actor_kernel),
                      hipFuncAttributeMaxDynamicSharedMemorySize, 108544);

  prep_kernel<<<1512, 256, 0, stream>>>(W1, W2, W3, ws);
  actor_kernel<<<2048, 256, 108544, stream>>>(state, eps, b1, b2, b3, ws, out);
}